// Round 10
// baseline (173.540 us; speedup 1.0000x reference)
//
#include <hip/hip_runtime.h>
#include <stdint.h>

// Problem constants (fixed by reference setup_inputs)
#define NPOS 512   // N
#define NH   64    // H
#define NM   1024  // M
#define NB   256   // B
#define NM1  511   // N-1

typedef __attribute__((ext_vector_type(8)))  short bf16x8;
typedef __attribute__((ext_vector_type(16))) float f32x16;
typedef __attribute__((ext_vector_type(4)))  float f32x4;
typedef __attribute__((ext_vector_type(4)))  int   i32x4;

#if __has_builtin(__builtin_amdgcn_exp2f)
#define EXP2F(x) __builtin_amdgcn_exp2f(x)
#else
#define EXP2F(x) __expf((x) * 0.69314718055994531f)
#endif

__device__ __forceinline__ unsigned short f2bf(float x) {
    unsigned u = __float_as_uint(x);
    u = (u + 0x7FFFu + ((u >> 16) & 1u)) >> 16;   // RNE
    return (unsigned short)u;
}
__device__ __forceinline__ int pack2(unsigned short a, unsigned short b) {
    return (int)a | ((int)b << 16);
}

// ---------------- kA: fused prep = {k0 seq->bf16 + zero out, k1a BnT softmax,
//                  k1c plusT transpose}. 272 blocks x 256 thr. ----------------
__global__ __launch_bounds__(256, 4)
void kA_prep(const float* __restrict__ seq, const float* __restrict__ Bl,
             const float* __restrict__ mem,
             unsigned short* __restrict__ seq_bf, float* __restrict__ BnT,
             float* __restrict__ plusT, float* __restrict__ out) {
    const int bid = blockIdx.x, t = threadIdx.x;
    if (bid < 128) {
        // --- k0: sequences fp32 -> bf16 (exact for +/-1) ---
        if (bid == 0 && t == 0) out[0] = 0.f;
        int idx = (bid * 256 + t) * 4;
        f32x4 v = *(const f32x4*)(seq + idx);
        int2 o;
        o.x = pack2(f2bf(v.x), f2bf(v.y));
        o.y = pack2(f2bf(v.z), f2bf(v.w));
        *(int2*)(seq_bf + idx) = o;
    } else if (bid < 144) {
        // --- k1a: Bn = softmax(B_logits, axis=-1), stored transposed ---
        const int h = (bid - 128) * 4 + (t >> 6), l = t & 63;
        float v[8]; float mx = -1e30f;
#pragma unroll
        for (int j = 0; j < 8; j++) { v[j] = Bl[h * NPOS + l + 64 * j]; mx = fmaxf(mx, v[j]); }
#pragma unroll
        for (int o = 32; o; o >>= 1) mx = fmaxf(mx, __shfl_xor(mx, o));
        float s = 0.f;
#pragma unroll
        for (int j = 0; j < 8; j++) { v[j] = __expf(v[j] - mx); s += v[j]; }
#pragma unroll
        for (int o = 32; o; o >>= 1) s += __shfl_xor(s, o);
        float r = 1.0f / s;
#pragma unroll
        for (int j = 0; j < 8; j++) BnT[(l + 64 * j) * NH + h] = v[j] * r;
    } else {
        // --- k1c: plusT[n][m] via LDS 64x64 tile transpose ---
        __shared__ float sT[64][65];
        const int bb = bid - 144;
        const int mt = bb >> 3, nt = bb & 7;
        const int rr = t >> 2, cc = t & 3;
        const float* src = mem + (size_t)(mt * 64 + rr) * NPOS + nt * 64 + cc * 16;
#pragma unroll
        for (int j = 0; j < 4; j++) {
            f32x4 v = *(const f32x4*)(src + j * 4);
            sT[rr][cc * 16 + j * 4 + 0] = (v.x > 0.f) ? 1.f : 0.f;
            sT[rr][cc * 16 + j * 4 + 1] = (v.y > 0.f) ? 1.f : 0.f;
            sT[rr][cc * 16 + j * 4 + 2] = (v.z > 0.f) ? 1.f : 0.f;
            sT[rr][cc * 16 + j * 4 + 3] = (v.w > 0.f) ? 1.f : 0.f;
        }
        __syncthreads();
        float* dst = plusT + (size_t)(nt * 64 + rr) * NM + mt * 64 + cc * 16;
#pragma unroll
        for (int j = 0; j < 4; j++) {
            f32x4 o;
            o.x = sT[cc * 16 + j * 4 + 0][rr];
            o.y = sT[cc * 16 + j * 4 + 1][rr];
            o.z = sT[cc * 16 + j * 4 + 2][rr];
            o.w = sT[cc * 16 + j * 4 + 3][rr];
            *(f32x4*)(dst + j * 4) = o;
        }
    }
}

// ---------------- k1b: phi_mu[m,h] = sum_n Bn[h,n]*memory[m,n] -> bf16 -------
// 512 blocks x 2 m-rows, 4 independent fma chains. PRE-SCALED by log2(e).
__global__ __launch_bounds__(256, 4)
void k1b_phimu(const float* __restrict__ BnT, const float* __restrict__ mem,
               unsigned short* __restrict__ phimu) {
    const int m0 = blockIdx.x * 2, t = threadIdx.x;
    __shared__ float mrow[2][NPOS];
    __shared__ float part[2][256];
    {
        int row = t >> 7, c = (t & 127) * 4;
        *(f32x4*)(&mrow[row][c]) = *(const f32x4*)(mem + (size_t)(m0 + row) * NPOS + c);
    }
    __syncthreads();
    const int h = t & 63, seg = t >> 6;
    float a[2] = {0.f, 0.f};
    float b2[2] = {0.f, 0.f};
    const float* bp = BnT + seg * 128 * NH + h;
#pragma unroll 8
    for (int nn = 0; nn < 128; nn += 2) {
        float x0 = bp[nn * NH], x1 = bp[(nn + 1) * NH];
#pragma unroll
        for (int row = 0; row < 2; row++) {
            a[row]  = fmaf(x0, mrow[row][seg * 128 + nn], a[row]);
            b2[row] = fmaf(x1, mrow[row][seg * 128 + nn + 1], b2[row]);
        }
    }
#pragma unroll
    for (int row = 0; row < 2; row++) part[row][t] = a[row] + b2[row];
    __syncthreads();
    if (t < 64) {
#pragma unroll
        for (int row = 0; row < 2; row++) {
            float s = (part[row][t] + part[row][t + 64]) + (part[row][t + 128] + part[row][t + 192]);
            phimu[(m0 + row) * NH + t] = f2bf(s * 1.4426950408889634f);  // * log2(e)
        }
    }
}

// ---------------- k23: FUSED hat_phi + retrieval softmax + BCE ---------------
// grid 511 (one block per n), *** 512 thr = 8 waves *** -> 2 blocks/CU = 16
// waves/CU (4/SIMD), double the 256-thr config (occupancy was grid-limited).
// lb(512,4): unified reg cap 128; phase-2 demand ~86 VGPR + 32 AGPR fits.
// Each wave owns a 32-b strip.
// Phase 1: E-tile dbuf (1 barrier/k-step), A-frags direct from L2-hot seq_bf,
//   E-exp spread over 512 thr (8 exps/lane/k-step), 2 accs/wave.
// Phase 2: 32 m-tiles, p prefetched 1 ahead, one MFMA chain + 16 exps/lane/iter,
//   exp2 streaming softmax (phimu pre-scaled log2e), wave-local BCE.
__global__ __launch_bounds__(512, 4)
void k23_fused(const float* __restrict__ Al, const unsigned short* __restrict__ seq_bf,
               const unsigned short* __restrict__ phimu, const float* __restrict__ plusT,
               const float* __restrict__ seq, float* __restrict__ out) {
    __shared__ __align__(16) unsigned short big[256 * 72];    // E dbuf (2x64x72) -> q tile (256x72)
    __shared__ float s_plus[NM];
    __shared__ float z_lds[64];

    const int t = threadIdx.x;
    const int n = NM1 - (int)blockIdx.x;          // n in 1..511, big n first
    const int ksteps = (n + 63) >> 6;
    const int wv = t >> 6, lane = t & 63, half = lane >> 5, r = lane & 31;

    if (t < 64) z_lds[t] = 0.f;
    // stage plus row early (independent of phase 1)
    if (t < 256) *(f32x4*)(s_plus + t * 4) = *(const f32x4*)(plusT + n * NM + t * 4);

    // ================= phase 1: hat_phi 256b x 64h tile =================
    const int eh = t >> 3, ei = (t & 7) * 8;      // 8 threads per E-row, 8 vals each
    const float* arow = Al + ((size_t)n * NH + eh) * NPOS + ei;
    // per-lane A-fragment source row (wave owns 32 b rows; L2-hot)
    const unsigned short* s0 = seq_bf + (size_t)(wv * 32 + r) * NPOS + half * 8;

    f32x16 acc0, acc1;
#pragma unroll
    for (int i = 0; i < 16; i++) { acc0[i] = 0.f; acc1[i] = 0.f; }

    f32x4 ea[2];
    ea[0] = *(const f32x4*)(arow);
    ea[1] = *(const f32x4*)(arow + 4);
    __syncthreads();   // z_lds init + s_plus staged

    for (int kk = 0; kk < ksteps; kk++) {
        const int k0 = kk * 64;
        unsigned short* ebuf = big + (kk & 1) * (64 * 72);
        // exp + stage E (8 vals/thread -> one b128 LDS store)
        {
            float zp = 0.f;
            int ev[4];
#pragma unroll
            for (int g = 0; g < 2; g++) {
                int i0 = k0 + ei + g * 4;
                float e0 = (i0 + 0 < n) ? __expf(ea[g].x) : 0.f;
                float e1 = (i0 + 1 < n) ? __expf(ea[g].y) : 0.f;
                float e2 = (i0 + 2 < n) ? __expf(ea[g].z) : 0.f;
                float e3 = (i0 + 3 < n) ? __expf(ea[g].w) : 0.f;
                zp += (e0 + e1) + (e2 + e3);
                ev[g * 2]     = pack2(f2bf(e0), f2bf(e1));
                ev[g * 2 + 1] = pack2(f2bf(e2), f2bf(e3));
            }
            *(i32x4*)(ebuf + eh * 72 + ei) = *(i32x4*)(ev);
            zp += __shfl_xor(zp, 1);
            zp += __shfl_xor(zp, 2);
            zp += __shfl_xor(zp, 4);
            if ((t & 7) == 0) z_lds[eh] += zp;
        }
        // prefetch next k-step's A_logits chunk
        if (kk + 1 < ksteps) {
            ea[0] = *(const f32x4*)(arow + k0 + 64);
            ea[1] = *(const f32x4*)(arow + k0 + 68);
        }
        __syncthreads();   // E[kk&1] visible (dbuf -> one barrier per k-step)
        // MFMA: D[b][h] += S[b,i] * E[h,i]
        {
            const unsigned short* sB0 = ebuf + r * 72 + half * 8;
            const unsigned short* sB1 = sB0 + 32 * 72;
#pragma unroll
            for (int kq = 0; kq < 4; kq++) {
                bf16x8 A  = *(const bf16x8*)(s0 + k0 + kq * 16);
                bf16x8 B0 = *(const bf16x8*)(sB0 + kq * 16);
                bf16x8 B1 = *(const bf16x8*)(sB1 + kq * 16);
                acc0 = __builtin_amdgcn_mfma_f32_32x32x16_bf16(A, B0, acc0, 0, 0, 0);
                acc1 = __builtin_amdgcn_mfma_f32_32x32x16_bf16(A, B1, acc1, 0, 0, 0);
            }
        }
    }
    __syncthreads();   // all E reads done -> big reusable as q tile
    // epilogue: scale by 1/Z[h], write q tile (rows wv*32+row, stride 72)
    {
        float rz0 = 1.0f / z_lds[r];
        float rz1 = 1.0f / z_lds[32 + r];
#pragma unroll
        for (int reg = 0; reg < 16; reg++) {
            int row = (reg & 3) + 8 * (reg >> 2) + 4 * half;
            big[(wv * 32 + row) * 72 + r]      = f2bf(acc0[reg] * rz0);
            big[(wv * 32 + row) * 72 + 32 + r] = f2bf(acc1[reg] * rz1);
        }
    }
    __syncthreads();

    // ================= phase 2: retrieval softmax =================
    // p tile 0 (global; issue first so it overlaps the q LDS reads)
    bf16x8 p[4];
#pragma unroll
    for (int kq = 0; kq < 4; kq++)
        p[kq] = *(const bf16x8*)(phimu + (r) * NH + kq * 16 + half * 8);
    // q fragments for this wave's 32 b (held in regs for all 32 m-tiles)
    bf16x8 q[4];
#pragma unroll
    for (int kq = 0; kq < 4; kq++)
        q[kq] = *(const bf16x8*)(big + (wv * 32 + r) * 72 + kq * 16 + half * 8);

    f32x4 den = {0.f,0.f,0.f,0.f}, num = {0.f,0.f,0.f,0.f};

    for (int it = 0; it < 32; ++it) {
        bf16x8 pn[4];
        if (it < 31) {   // prefetch next m-tile (no barrier in loop: stays in flight)
#pragma unroll
            for (int kq = 0; kq < 4; kq++)
                pn[kq] = *(const bf16x8*)(phimu + ((it + 1) * 32 + r) * NH + kq * 16 + half * 8);
        }
        f32x16 a;
#pragma unroll
        for (int i = 0; i < 16; i++) a[i] = 0.f;
#pragma unroll
        for (int kq = 0; kq < 4; kq++)
            a = __builtin_amdgcn_mfma_f32_32x32x16_bf16(p[kq], q[kq], a, 0, 0, 0);
        const int mb = it * 32;
#pragma unroll
        for (int g = 0; g < 4; g++) {
            f32x4 pv = *(const f32x4*)(s_plus + mb + 4 * half + 8 * g);
            f32x4 e;
#pragma unroll
            for (int j = 0; j < 4; j++)
                e[j] = EXP2F(a[4 * g + j]);      // m = mb + j + 8*g + 4*half
            den += e; num += e * pv;
        }
        if (it < 31) {
#pragma unroll
            for (int kq = 0; kq < 4; kq++) p[kq] = pn[kq];
        }
    }
    float d  = (den[0] + den[1]) + (den[2] + den[3]);
    float nu = (num[0] + num[1]) + (num[2] + num[3]);
    // combine the two m-halves (same b = wv*32 + r, complementary m rows)
    d += __shfl_xor(d, 32); nu += __shfl_xor(nu, 32);

    // BCE on half==0 lanes (complete den/num for b = wv*32 + r)
    float bce = 0.f;
    if (half == 0) {
        float p2 = nu / d;
        p2 = fminf(fmaxf(p2, 1e-6f), 1.0f - 1e-6f);
        float tg = seq[(size_t)(wv * 32 + r) * NPOS + n];
        bce = (tg > 0.f) ? -logf(p2) : -logf(1.0f - p2);
    }
#pragma unroll
    for (int o = 32; o; o >>= 1) bce += __shfl_xor(bce, o);
    if (lane == 0) z_lds[wv] = bce;     // z_lds dead after epilogue rz reads
    __syncthreads();
    if (t == 0) {
        float s = 0.f;
#pragma unroll
        for (int w = 0; w < 8; w++) s += z_lds[w];
        atomicAdd(out, s * (1.0f / 130816.0f));
    }
}

extern "C" void kernel_launch(void* const* d_in, const int* in_sizes, int n_in,
                              void* d_out, int out_size, void* d_ws, size_t ws_size,
                              hipStream_t stream) {
    const float* seq = (const float*)d_in[0];  // (B,N)
    const float* mem = (const float*)d_in[1];  // (M,N)
    const float* Al  = (const float*)d_in[2];  // (N,H,N)
    const float* Bl  = (const float*)d_in[3];  // (H,N)

    char* ws = (char*)d_ws;
    unsigned short* seq_bf = (unsigned short*)(ws + 0);          // 256 KB
    float*          BnT    = (float*)(ws + 262144);              // 128 KB (N,H)
    unsigned short* phimu  = (unsigned short*)(ws + 393216);     // 128 KB (M,H) *log2e
    float*          plusT  = (float*)(ws + 524288);              // 2 MB (N,M)
    float*          outp   = (float*)d_out;

    kA_prep<<<272, 256, 0, stream>>>(seq, Bl, mem, seq_bf, BnT, plusT, outp);
    k1b_phimu<<<512, 256, 0, stream>>>(BnT, mem, phimu);
    k23_fused<<<511, 512, 0, stream>>>(Al, seq_bf, phimu, plusT, seq, outp);
}